// Round 14
// baseline (83.618 us; speedup 1.0000x reference)
//
#include <hip/hip_runtime.h>

#define NB 4
#define NN 2048
#define NF 256
#define NK 4
#define ND 64
#define NEG 0.2f
#define LOG2E 1.4426950408889634f

typedef _Float16 f16;
typedef _Float16 f16x2 __attribute__((ext_vector_type(2)));
typedef _Float16 f16x4 __attribute__((ext_vector_type(4)));
typedef _Float16 f16x8 __attribute__((ext_vector_type(8)));
typedef float f32x4 __attribute__((ext_vector_type(4)));
typedef float f32x16 __attribute__((ext_vector_type(16)));
typedef unsigned int u32;
typedef unsigned short u16;

// ---------------------------------------------------------------------------
// K01: unchanged from R13 (proven). k1 (blocks 0..255) + k0 (256..2303).
// k1: Wh^T per (b,k), f16, OCTET-MAJOR:
//     elem(d, j) at wht[(b*NK+k)*131072 + (j>>3)*512 + d*8 + (j&7)]
//   Epilogue: s -> sbuf(f32); t -> E=exp(t), F=exp(0.2t) as f16.
// k0: abit[b][i][jw] = bits of (adj>0 | I), 64 words/row.
// ---------------------------------------------------------------------------
__global__ __launch_bounds__(256) void k01(
    const float* __restrict__ x,      // (B,N,F)
    const int*   __restrict__ adj,    // (B,N,N)
    const float* __restrict__ Wm,     // (K,F,D)
    const float* __restrict__ a_src,  // (K,D)
    const float* __restrict__ a_dst,  // (K,D)
    unsigned int* __restrict__ abit,  // (B,N,64)
    f16* __restrict__ wht,            // octet-major
    float* __restrict__ sbuf,         // (B,K,N) f32
    f16* __restrict__ ebuf,           // (B,K,N) f16 exp(t)
    f16* __restrict__ fbuf)           // (B,K,N) f16 exp(0.2 t)
{
    __shared__ f16 wt[64 * 256];  // k1 only: W^T, xor-swizzled in f

    const int bx  = blockIdx.x;
    const int tid = threadIdx.x;

    if (bx >= 256) {
        // ---------------- k0: bit-pack ----------------
        const int row = (bx - 256) * 4 + (tid >> 6);  // b*NN + i
        const int l   = tid & 63;
        const int i   = row & (NN - 1);
        const int* __restrict__ ar = adj + (size_t)row * NN;

        int v[32];
#pragma unroll
        for (int c = 0; c < 32; ++c) v[c] = ar[c * 64 + l];

        unsigned int kx = 0, ky = 0;
#pragma unroll
        for (int c = 0; c < 32; ++c) {
            unsigned long long m = __ballot(v[c] > 0);
            if (l == c) { kx = (unsigned int)m; ky = (unsigned int)(m >> 32); }
        }
        if (l == (i >> 6)) {          // self-loop bit
            unsigned int sb = 1u << (i & 31);
            if (((i >> 5) & 1) == 0) kx |= sb; else ky |= sb;
        }
        if (l < 32) {
            uint2 kk; kk.x = kx; kk.y = ky;
            *(uint2*)&abit[(size_t)row * 64 + l * 2] = kk;
        }
        return;
    }

    // ---------------- k1: GEMM ----------------
    const int gx  = bx & 15;      // n-group of 128
    const int k   = (bx >> 4) & 3;
    const int b   = bx >> 6;
    const int wv  = tid >> 6;
    const int l   = tid & 63;
    const int q   = l >> 4;
    const int r16 = l & 15;

    for (int fc = 0; fc < 64; ++fc) {
        int f = fc * 4 + wv;
        int d = l;
        wt[d * 256 + (f ^ ((d & 7) << 3))] = (f16)Wm[(k * NF + f) * ND + d];
    }
    __syncthreads();

    const int ncol0 = gx * 128 + wv * 32;
    f32x4 acc[2][4];
#pragma unroll
    for (int nt = 0; nt < 2; ++nt)
#pragma unroll
        for (int dt = 0; dt < 4; ++dt)
            acc[nt][dt] = (f32x4){0.f, 0.f, 0.f, 0.f};

    for (int fs = 0; fs < 16; ++fs) {           // K-steps of 16
        const int f0 = fs * 16 + q * 4;
        f16x4 af[4];
#pragma unroll
        for (int dt = 0; dt < 4; ++dt) {
            int d = dt * 16 + r16;
            af[dt] = *(const f16x4*)&wt[d * 256 + (f0 ^ ((d & 7) << 3))];
        }
#pragma unroll
        for (int nt = 0; nt < 2; ++nt) {
            int n = ncol0 + nt * 16 + r16;
            float4 xv = *(const float4*)&x[((size_t)(b * NN + n)) * NF + f0];
            f16x4 bf = {(f16)xv.x, (f16)xv.y, (f16)xv.z, (f16)xv.w};
#pragma unroll
            for (int dt = 0; dt < 4; ++dt)
                acc[nt][dt] = __builtin_amdgcn_mfma_f32_16x16x16f16(
                    af[dt], bf, acc[nt][dt], 0, 0, 0);
        }
    }

    float asv[4][4], adv[4][4];
#pragma unroll
    for (int dt = 0; dt < 4; ++dt)
#pragma unroll
        for (int rr = 0; rr < 4; ++rr) {
            int d = dt * 16 + q * 4 + rr;
            asv[dt][rr] = a_src[k * ND + d];
            adv[dt][rr] = a_dst[k * ND + d];
        }

    const size_t obase = (size_t)(b * NK + k) * 131072;

#pragma unroll
    for (int nt = 0; nt < 2; ++nt) {
        int n  = ncol0 + nt * 16 + r16;
        const size_t sb_ = obase + (size_t)(n >> 3) * 512 + (n & 7);
        float sp = 0.f, tp = 0.f;
#pragma unroll
        for (int dt = 0; dt < 4; ++dt)
#pragma unroll
            for (int rr = 0; rr < 4; ++rr) {
                float v = acc[nt][dt][rr];
                int d = dt * 16 + q * 4 + rr;    // C row = d'
                wht[sb_ + d * 8] = (f16)v;
                sp += v * asv[dt][rr];
                tp += v * adv[dt][rr];
            }
        sp += __shfl_xor(sp, 16);
        sp += __shfl_xor(sp, 32);
        tp += __shfl_xor(tp, 16);
        tp += __shfl_xor(tp, 32);
        if (q == 0) {
            int idx = (b * NK + k) * NN + n;
            sbuf[idx] = sp;
            ebuf[idx] = (f16)__builtin_exp2f(tp * LOG2E);
            fbuf[idx] = (f16)__builtin_exp2f(0.2f * LOG2E * tp);
        }
    }
}

// ---------------------------------------------------------------------------
// K2 v13: M=64 rows per wave — each fragment load feeds 4 MFMAs (was 2),
// halving L2 fragment traffic (256->128MB). Block = 256 thr = 4 waves = 4
// j-chunks (512 j each), ALL waves share the same 64 rows. Grid 512 =
// 16 bkv (XCD-pinned) x 32 rg. Denominator via fdot2 (2 VGPR, v8-proven).
// Chunk combine via LDS atomicAdd f32 (accbuf 16KB) — no 72KB stash.
// VGPR budget ~120 -> launch_bounds(256,4) caps 128, 16 waves/CU.
// ---------------------------------------------------------------------------
__global__ __launch_bounds__(256, 4) void k2_attn(
    const unsigned int* __restrict__ abit,  // (B,N,64) bit-mask
    const f16* __restrict__ wht,            // octet-major
    const float* __restrict__ sbuf,         // (B,K,N)
    const f16* __restrict__ ebuf,           // (B,K,N) f16
    const f16* __restrict__ fbuf,           // (B,K,N) f16
    float* __restrict__ out)                // (B,N,K*D)
{
    const int bid = blockIdx.x;
    const int bkv = (bid & 7) | (((bid >> 3) & 1) << 3);  // XCD-pinned (b,k)
    const int rg  = bid >> 4;                             // row-group 0..31
    const int b   = bkv >> 2, k = bkv & 3;
    const int i0  = rg * 64;
    const int tid = threadIdx.x;
    const int w   = tid >> 6;        // wave = j-chunk 0..3
    const int l   = tid & 63;
    const int r32 = l & 31;
    const int hi  = l >> 5;
    const int row_a = i0 + r32;          // rowset a: i0..i0+31
    const int row_b = i0 + 32 + r32;     // rowset b: i0+32..i0+63

    // LDS: accbuf f32[64][64] @0 (16KB); dden f32[64] @16384; el @16640 (4KB);
    // fl @20736 (4KB). Total 24832B -> 4+ blocks/CU.
    __shared__ __attribute__((aligned(16))) char pool[24832];
    float* accbuf = (float*)pool;
    float* dden   = (float*)(pool + 16384);
    u16*   el     = (u16*)(pool + 16640);
    u16*   fl     = (u16*)(pool + 20736);

    // zero the combine region (4160 dwords / 256 thr)
#pragma unroll
    for (int z = 0; z < 17; ++z) {
        int idx = z * 256 + tid;
        if (idx < 4160) accbuf[idx] = 0.f;
    }
    {   // stage E/F as f16 (4KB each), coalesced, once
        const u16* eb = (const u16*)(ebuf + bkv * NN);
        const u16* fb = (const u16*)(fbuf + bkv * NN);
        *(uint4*)&el[tid * 8] = *(const uint4*)&eb[tid * 8];
        *(uint4*)&fl[tid * 8] = *(const uint4*)&fb[tid * 8];
    }

    const float s_a = sbuf[bkv * NN + row_a];
    const float s_b = sbuf[bkv * NN + row_b];
    const f16 Afa = (f16)__builtin_exp2f(0.8f * LOG2E * fminf(s_a, 0.f));
    const f16 Bfa = (f16)__builtin_exp2f(-0.8f * LOG2E * fmaxf(s_a, 0.f));
    const f16 Afb = (f16)__builtin_exp2f(0.8f * LOG2E * fminf(s_b, 0.f));
    const f16 Bfb = (f16)__builtin_exp2f(-0.8f * LOG2E * fmaxf(s_b, 0.f));
    const f16x2 Af2a = {Afa, Afa}, Bf2a = {Bfa, Bfa};
    const f16x2 Af2b = {Afb, Afb}, Bf2b = {Bfb, Bfb};
    const f16x2 one2 = {(f16)1.0f, (f16)1.0f};

    const unsigned int* __restrict__ abrow_a =
        abit + (size_t)(b * NN + row_a) * 64 + w * 16;
    const unsigned int* __restrict__ abrow_b = abrow_a + 32 * 64;

    // lane-constant fragment base: octet s = w*64 + it*8 + jts*2 + hi
    const f16* __restrict__ lanep =
        wht + (size_t)bkv * 131072 + (size_t)(w * 64 + hi) * 512 + r32 * 8;

    float den_a = 0.f, den_b = 0.f;
    f32x16 acc[4];   // [0]=a rows x d0-31, [1]=a x d32-63, [2]=b x d0-31, [3]=b x d32-63
#pragma unroll
    for (int t = 0; t < 4; ++t)
#pragma unroll
        for (int z = 0; z < 16; ++z) acc[t][z] = 0.f;

    __syncthreads();   // accbuf zeroed + el/fl visible

// build masked pa for one rowset; accumulates its denom via fdot2
#define PABUILD(PA, DEN, AF2, BF2, WORD)                                       \
    do {                                                                       \
        const u32 bbyte = ((WORD) >> (((jts & 1) << 4) + (hi << 3))) & 0xffu;  \
        const u32 u = (bbyte << 15) | bbyte;                                   \
        u32 pa_u[4];                                                           \
        _Pragma("unroll") for (int p = 0; p < 4; ++p) {                        \
            f16x2 e2 = __builtin_bit_cast(f16x2, ((const u32*)&E4)[p]);        \
            f16x2 f2 = __builtin_bit_cast(f16x2, ((const u32*)&F4)[p]);        \
            f16x2 w2 = __builtin_elementwise_max((AF2) * e2, (BF2) * f2);      \
            u32 xx = (u >> (2 * p)) & 0x00010001u;                             \
            u32 mm = (xx << 16) - xx;                                          \
            pa_u[p] = __builtin_bit_cast(u32, w2) & mm;                        \
            DEN = __builtin_amdgcn_fdot2(                                      \
                __builtin_bit_cast(f16x2, pa_u[p]), one2, DEN, false);         \
        }                                                                      \
        uint4 pav = {pa_u[0], pa_u[1], pa_u[2], pa_u[3]};                      \
        PA = __builtin_bit_cast(f16x8, pav);                                   \
    } while (0)

#pragma unroll
    for (int it = 0; it < 8; ++it) {
        const uint2 ab_a = *(const uint2*)(abrow_a + it * 2);
        const uint2 ab_b = *(const uint2*)(abrow_b + it * 2);
#pragma unroll
        for (int jts = 0; jts < 4; ++jts) {
            const int jb = w * 512 + it * 64 + jts * 16 + hi * 8;
            uint4 E4 = *(const uint4*)&el[jb];       // broadcast reads
            uint4 F4 = *(const uint4*)&fl[jb];
            const u32 word_a = (jts & 2) ? ab_a.y : ab_a.x;
            const u32 word_b = (jts & 2) ? ab_b.y : ab_b.x;
            f16x8 pa_a, pa_b;
            PABUILD(pa_a, den_a, Af2a, Bf2a, word_a);
            PABUILD(pa_b, den_b, Af2b, Bf2b, word_b);

            // fragments: octet (it*8 + jts*2 + hi); serve BOTH rowsets
            const f16* fp = lanep + (size_t)(it * 8 + jts * 2) * 512;
            f16x8 v80 = *(const f16x8*)(fp);         // d 0..31
            f16x8 v81 = *(const f16x8*)(fp + 256);   // d 32..63
            acc[0] = __builtin_amdgcn_mfma_f32_32x32x16_f16(pa_a, v80, acc[0], 0, 0, 0);
            acc[1] = __builtin_amdgcn_mfma_f32_32x32x16_f16(pa_a, v81, acc[1], 0, 0, 0);
            acc[2] = __builtin_amdgcn_mfma_f32_32x32x16_f16(pa_b, v80, acc[2], 0, 0, 0);
            acc[3] = __builtin_amdgcn_mfma_f32_32x32x16_f16(pa_b, v81, acc[3], 0, 0, 0);
        }
    }
#undef PABUILD

    // chunk-local row denominators: combine the two hi-halves
    den_a += __shfl_xor(den_a, 32);
    den_b += __shfl_xor(den_b, 32);
    if (hi == 0) {
        atomicAdd(&dden[r32], den_a);
        atomicAdd(&dden[32 + r32], den_b);
    }

    // scatter acc into the shared combine buffer (ds_add_f32, conflict-light:
    // lanes hit distinct d -> distinct banks; 2-way hi alias is free)
#pragma unroll
    for (int t = 0; t < 4; ++t) {
        const int rbase = (t >> 1) * 32 + hi * 4;
        const int d = (t & 1) * 32 + r32;
#pragma unroll
        for (int rr = 0; rr < 16; ++rr) {
            const int row = rbase + (rr & 3) + 8 * (rr >> 2);  // C/D map (m74/m101)
            atomicAdd(&accbuf[row * 64 + d], acc[t][rr]);
        }
    }
    __syncthreads();

    // epilogue: wave w writes rows w*16 .. w*16+15 (coalesced in d = lane)
    float* op = out + ((size_t)(b * NN) + i0) * (NK * ND) + k * ND;
#pragma unroll
    for (int r = 0; r < 16; ++r) {
        const int row = w * 16 + r;
        const float inv = 1.f / (dden[row] + 1e-10f);
        op[(size_t)row * (NK * ND) + l] = accbuf[row * 64 + l] * inv;
    }
}

extern "C" void kernel_launch(void* const* d_in, const int* in_sizes, int n_in,
                              void* d_out, int out_size, void* d_ws, size_t ws_size,
                              hipStream_t stream) {
    const float* x     = (const float*)d_in[0];
    const int*   adj   = (const int*)d_in[1];
    const float* Wm    = (const float*)d_in[2];
    const float* a_src = (const float*)d_in[3];
    const float* a_dst = (const float*)d_in[4];
    float* out = (float*)d_out;

    char* ws = (char*)d_ws;
    f16*   wht  = (f16*)ws;                                   // 4 MiB
    float* sbuf = (float*)(ws + (4u << 20));                  // 128 KiB
    f16*   ebuf = (f16*)(ws + (4u << 20) + (128u << 10));     // 64 KiB
    f16*   fbuf = (f16*)(ws + (4u << 20) + (192u << 10));     // 64 KiB
    unsigned int* abit = (unsigned int*)(ws + (4u << 20) + (256u << 10)); // 2 MiB

    k01<<<dim3(256 + NB * NN / 4), 256, 0, stream>>>(
        x, adj, Wm, a_src, a_dst, abit, wht, sbuf, ebuf, fbuf);
    k2_attn<<<dim3(512), 256, 0, stream>>>(
        abit, wht, sbuf, ebuf, fbuf, out);
}